// Round 5
// baseline (6836.832 us; speedup 1.0000x reference)
//
#include <hip/hip_runtime.h>
#include <math.h>

#define BATCH 8
#define CH 64
#define HW 96
#define HQ 47
#define LQ 2209         // 47*47
#define LP 2304         // padded to 18*128
#define KD 1600         // 64*25
#define NC9 576         // 64*9
#define NTILE 18        // LP/128 l-tiles
#define MARGIN 1.5e-3f  // bf16-screen near-tie window (det. bound 2.5e-3, RMS 4e-5)

typedef __attribute__((ext_vector_type(8))) short short8;   // 8 bf16 (4 VGPR)
typedef __attribute__((ext_vector_type(4))) float f32x4;    // MFMA C/D frag

// ---------------------------------------------------------------------------
// numpy pairwise sum of squares (blocksize 128, 8 accumulators) — exact
// emulation of numpy's pairwise_sum over a contiguous fp32 axis.
// ---------------------------------------------------------------------------
__device__ float np_pairwise_sq(const float* a, int n) {
#pragma clang fp contract(off)
  if (n <= 128) {
    float r[8];
#pragma unroll
    for (int j = 0; j < 8; ++j) { float x = a[j]; r[j] = x * x; }
    int nm8 = n - (n % 8);
    for (int i = 8; i < nm8; i += 8)
#pragma unroll
      for (int j = 0; j < 8; ++j) { float x = a[i + j]; r[j] = r[j] + x * x; }
    float res = ((r[0] + r[1]) + (r[2] + r[3])) + ((r[4] + r[5]) + (r[6] + r[7]));
    for (int i = nm8; i < n; ++i) { float x = a[i]; res = res + x * x; }
    return res;
  }
  int n2 = n / 2;
  n2 -= n2 % 8;
  float s0 = np_pairwise_sq(a, n2);
  float s1 = np_pairwise_sq(a + n2, n - n2);
  return s0 + s1;
}

// ---------------------------------------------------------------------------
// prep: unfold (k=5,p=1,s=2), L2-normalize with numpy-exact fp32 rounding.
// mode 0 (key):  norm via pairwise-128 (contig axis); mode 1 (query):
// sequential-in-c (middle-axis reduce). rows >= LQ zero-filled.
// ---------------------------------------------------------------------------
__global__ __launch_bounds__(256) void prep_np_kernel(
    const float* __restrict__ src, float* __restrict__ out, int mode) {
  __shared__ float sRaw[KD];
  __shared__ float sDen;
  const int pos = blockIdx.x;
  const int b = blockIdx.y;
  const int t = threadIdx.x;
  const size_t obase = ((size_t)b * LP + pos) * KD;

  if (pos >= LQ) {
    for (int k = t; k < KD; k += 256) out[obase + k] = 0.f;
    return;
  }
  const int y0 = (pos / HQ) * 2 - 1, x0 = (pos % HQ) * 2 - 1;
  for (int k = t; k < KD; k += 256) {
    const int c = k / 25, r = k % 25, kh = r / 5, kw = r % 5;
    const int y = y0 + kh, x = x0 + kw;
    float v = 0.f;
    if (y >= 0 && y < HW && x >= 0 && x < HW)
      v = src[(((size_t)b * CH + c) * HW + y) * HW + x];
    sRaw[k] = v;
  }
  __syncthreads();
  if (t == 0) {
    float ss;
    if (mode == 0) {
      ss = np_pairwise_sq(sRaw, KD);
    } else {
#pragma clang fp contract(off)
      float acc = 0.f;
      for (int k2 = 0; k2 < KD; ++k2) {
        float x = sRaw[k2];
        float p = x * x;
        acc = acc + p;
      }
      ss = acc;
    }
    float nrm = (float)sqrt((double)ss);
    sDen = fmaxf(nrm, 1e-12f);
  }
  __syncthreads();
  const float den = sDen;
  for (int k = t; k < KD; k += 256) out[obase + k] = sRaw[k] / den;
}

// ---------------------------------------------------------------------------
// helpers for bf16 MFMA brute
// ---------------------------------------------------------------------------
__device__ inline unsigned f2bf2(float lo, float hi) {
  // RNE fp32->bf16, packed pair (lo in low 16 bits)
  unsigned a = __float_as_uint(lo); a = (a + 0x7fffu + ((a >> 16) & 1u)) >> 16;
  unsigned b = __float_as_uint(hi); b = (b + 0x7fffu + ((b >> 16) & 1u)) >> 16;
  return a | (b << 16);
}

__device__ inline void cvt_store8(short* lds, int byteoff, const float* g) {
  const float4 f0 = *(const float4*)g;
  const float4 f1 = *(const float4*)(g + 4);
  int4 wv;
  wv.x = (int)f2bf2(f0.x, f0.y);
  wv.y = (int)f2bf2(f0.z, f0.w);
  wv.z = (int)f2bf2(f1.x, f1.y);
  wv.w = (int)f2bf2(f1.z, f1.w);
  *(int4*)((char*)lds + byteoff) = wv;
}

__device__ inline void top2_merge(float& v1, int& l1, float& v2, int& l2,
                                  float b1, int a1, float b2, int a2) {
  if (b1 > v1 || (b1 == v1 && a1 < l1)) {
    float nv2; int nl2;
    if (v1 > b2 || (v1 == b2 && l1 < a2)) { nv2 = v1; nl2 = l1; }
    else { nv2 = b2; nl2 = a2; }
    v1 = b1; l1 = a1; v2 = nv2; l2 = nl2;
  } else if (b1 > v2 || (b1 == v2 && a1 < l2)) {
    v2 = b1; l2 = a1;
  }
}

// ---------------------------------------------------------------------------
// brute_mfma: bf16 MFMA SCREENING pass on the matrix pipe.
// Grid (18,18,8); block 256 = 4 waves in 2x2; tile 128l x 128q; per wave
// 64x64 via 4x4 MFMA 16x16x32 frags. fp32 kn/qn converted to bf16 in-flight
// into XOR-swizzled [128][64] bf16 LDS tiles (rows 128B, byte^=(row&7)<<4).
// Per-tile top-2 over l per q via in-lane top2 + shfl_xor(16/32) butterfly.
// Screen err: RMS ~4e-5, det-bound ~2.5e-3 -> MARGIN covers; refine is the
// unconditional backstop for flagged queries.
// ---------------------------------------------------------------------------
__global__ __launch_bounds__(256) void brute_mfma_kernel(
    const float* __restrict__ kn, const float* __restrict__ qn,
    float* __restrict__ tV1, int* __restrict__ tL1,
    float* __restrict__ tV2, int* __restrict__ tL2) {
  __shared__ __align__(16) short sKb[128 * 64];
  __shared__ __align__(16) short sQb[128 * 64];
  __shared__ float sWv1[2][128];
  __shared__ float sWv2[2][128];
  __shared__ int sWl1[2][128];
  __shared__ int sWl2[2][128];

  const int t = threadIdx.x;
  const int qt = blockIdx.x, lt = blockIdx.y, b = blockIdx.z;
  const int l0 = lt * 128, q0 = qt * 128;
  const int w = t >> 6, lane = t & 63;
  const int wl = w >> 1, wq = w & 1;
  const int cl = lane & 15, g = lane >> 4;

  f32x4 acc[4][4];
#pragma unroll
  for (int i = 0; i < 4; ++i)
#pragma unroll
    for (int j = 0; j < 4; ++j) {
      f32x4 z = {0.f, 0.f, 0.f, 0.f};
      acc[i][j] = z;
    }

  const size_t kbase = ((size_t)(b * LP + l0)) * KD;
  const size_t qbase = ((size_t)(b * LP + q0)) * KD;

  // staging map: 1024 16B-slots per array; chunk c: slot_id = c*256+t
  int srow[4], sslot[4], soff[4];
#pragma unroll
  for (int c = 0; c < 4; ++c) {
    const int sid = c * 256 + t;
    srow[c] = sid >> 3;
    sslot[c] = sid & 7;
    soff[c] = srow[c] * 128 + ((sslot[c] ^ (srow[c] & 7)) * 16);
  }

  for (int c0 = 0; c0 < KD; c0 += 64) {
    __syncthreads();  // previous iteration's frag reads done
#pragma unroll
    for (int c = 0; c < 4; ++c) {
      const float* gk = kn + kbase + (size_t)srow[c] * KD + c0 + sslot[c] * 8;
      const float* gq = qn + qbase + (size_t)srow[c] * KD + c0 + sslot[c] * 8;
      cvt_store8(sKb, soff[c], gk);
      cvt_store8(sQb, soff[c], gq);
    }
    __syncthreads();
#pragma unroll
    for (int kk = 0; kk < 2; ++kk) {
      short8 Af[4], Bf[4];
#pragma unroll
      for (int i = 0; i < 4; ++i) {
        const int ar = wl * 64 + i * 16 + cl;
        Af[i] = *(const short8*)((const char*)sKb + ar * 128 +
                                 (((kk * 4 + g) ^ (ar & 7)) * 16));
        const int br = wq * 64 + i * 16 + cl;
        Bf[i] = *(const short8*)((const char*)sQb + br * 128 +
                                 (((kk * 4 + g) ^ (br & 7)) * 16));
      }
#pragma unroll
      for (int i = 0; i < 4; ++i)
#pragma unroll
        for (int j = 0; j < 4; ++j)
          acc[i][j] = __builtin_amdgcn_mfma_f32_16x16x32_bf16(
              Af[i], Bf[j], acc[i][j], 0, 0, 0);
    }
  }

  // per-wave top-2 over its 64 l's, per q column
#pragma unroll
  for (int j = 0; j < 4; ++j) {
    float v1 = -1e30f, v2 = -1e30f;
    int l1 = 0x7fffffff, l2 = 0x7fffffff;
#pragma unroll
    for (int i = 0; i < 4; ++i)
#pragma unroll
      for (int r = 0; r < 4; ++r) {
        const int ll = l0 + wl * 64 + i * 16 + g * 4 + r;   // ascending per lane
        const float v = (ll < LQ) ? acc[i][j][r] : -1e30f;
        if (v > v1) { v2 = v1; l2 = l1; v1 = v; l1 = ll; }
        else if (v > v2) { v2 = v; l2 = ll; }
      }
#pragma unroll
    for (int m = 16; m < 64; m <<= 1) {
      const float b1 = __shfl_xor(v1, m, 64);
      const int a1 = __shfl_xor(l1, m, 64);
      const float b2 = __shfl_xor(v2, m, 64);
      const int a2 = __shfl_xor(l2, m, 64);
      top2_merge(v1, l1, v2, l2, b1, a1, b2, a2);
    }
    if (g == 0) {
      const int qq = wq * 64 + j * 16 + cl;
      sWv1[wl][qq] = v1; sWl1[wl][qq] = l1;
      sWv2[wl][qq] = v2; sWl2[wl][qq] = l2;
    }
  }
  __syncthreads();
  if (t < 128) {
    float v1 = sWv1[0][t], v2 = sWv2[0][t];
    int l1 = sWl1[0][t], l2 = sWl2[0][t];
    top2_merge(v1, l1, v2, l2, sWv1[1][t], sWl1[1][t], sWv2[1][t], sWl2[1][t]);
    const int q = q0 + t;
    if (q < LQ) {
      const size_t o = ((size_t)b * LP + q) * NTILE + lt;
      tV1[o] = v1; tL1[o] = l1; tV2[o] = v2; tL2[o] = l2;
    }
  }
}

// ---------------------------------------------------------------------------
// finalize32: merge 18 tiles -> screen top-2. Gap >= MARGIN guarantees the
// screen argmax == exact fp32-rounded argmax (screen error bound + union of
// per-tile candidates). Otherwise flag for exact refinement.
// ---------------------------------------------------------------------------
__global__ __launch_bounds__(256) void finalize32_kernel(
    const float* __restrict__ tV1, const int* __restrict__ tL1,
    const float* __restrict__ tV2, const int* __restrict__ tL2,
    float* __restrict__ S, int* __restrict__ final_l,
    int* __restrict__ flag_list, int* __restrict__ flag_cnt) {
  const int q = blockIdx.x * 256 + threadIdx.x;
  const int b = blockIdx.z;
  if (q >= LQ) return;
  const size_t base = ((size_t)b * LP + q) * NTILE;
  float v1 = -1e30f, v2 = -1e30f;
  int l1 = 0x7fffffff, l2 = 0x7fffffff;
  for (int i = 0; i < NTILE; ++i)
    top2_merge(v1, l1, v2, l2, tV1[base + i], tL1[base + i],
               tV2[base + i], tL2[base + i]);
  S[b * LQ + q] = v1;
  final_l[b * LQ + q] = l1;
  if ((v1 - v2) < MARGIN) {
    const int slot = atomicAdd(flag_cnt, 1);
    flag_list[slot] = b * LQ + q;
  }
}

// ---------------------------------------------------------------------------
// refine: for flagged queries, recompute the ENTIRE row of exact fp64 dots
// and take np.argmax over the fp32-rounded values (first-index tie rule).
// Unconditionally correct regardless of screening accuracy.
// ---------------------------------------------------------------------------
__global__ __launch_bounds__(256) void refine_kernel(
    const int* __restrict__ flag_list, const int* __restrict__ flag_cnt,
    const float* __restrict__ kn, const float* __restrict__ qn,
    float* __restrict__ S, int* __restrict__ final_l) {
  __shared__ float sQrow[KD];
  __shared__ float sF[256];
  __shared__ int sL[256];
  const int n = *flag_cnt;
  const int t = threadIdx.x;
  for (int e = blockIdx.x; e < n; e += gridDim.x) {
    const int bq = flag_list[e];
    const int b = bq / LQ, q = bq % LQ;
    __syncthreads();  // protect sQrow reuse across iterations
    for (int k = t; k < KD; k += 256)
      sQrow[k] = qn[((size_t)b * LP + q) * KD + k];
    __syncthreads();
    float bf = -1e30f; int bl = -1;
    for (int l = t; l < LQ; l += 256) {   // ascending l per thread
      const float* kr = kn + ((size_t)b * LP + l) * KD;
      double acc = 0.0;
      for (int c = 0; c < KD; ++c)
        acc = fma((double)kr[c], (double)sQrow[c], acc);
      const float f = (float)acc;         // fp32-rounded exact dot
      if (f > bf) { bf = f; bl = l; }     // strict > keeps first index
    }
    sF[t] = bf; sL[t] = bl;
    __syncthreads();
    for (int s = 128; s > 0; s >>= 1) {
      if (t < s) {
        const float of = sF[t + s]; const int ol = sL[t + s];
        if (of > sF[t] || (of == sF[t] && ol < sL[t])) { sF[t] = of; sL[t] = ol; }
      }
      __syncthreads();
    }
    if (t == 0) { S[b * LQ + q] = sF[0]; final_l[b * LQ + q] = sL[0]; }
  }
}

// ---------------------------------------------------------------------------
// gather: value patches (k=3,p=1,s=1) at argmax positions.
// ---------------------------------------------------------------------------
__global__ __launch_bounds__(256) void gather_kernel(
    const int* __restrict__ final_l, const float* __restrict__ value,
    float* __restrict__ T) {
  const int q = blockIdx.x * 256 + threadIdx.x;
  const int g = blockIdx.y;
  const int b = blockIdx.z;
  if (q >= LQ) return;
  const int l = final_l[b * LQ + q];
  const int y0 = l / HW - 1;
  const int x0 = l % HW - 1;
#pragma unroll
  for (int cc = 0; cc < 36; ++cc) {
    const int c9 = g * 36 + cc;
    const int c = c9 / 9, r = c9 % 9;
    const int kh = r / 3, kw = r % 3;
    const int y = y0 + kh, x = x0 + kw;
    float v = 0.f;
    if (y >= 0 && y < HW && x >= 0 && x < HW)
      v = value[(((size_t)b * CH + c) * HW + y) * HW + x];
    T[((size_t)(b * NC9 + c9)) * LQ + q] = v;
  }
}

// ---------------------------------------------------------------------------
extern "C" void kernel_launch(void* const* d_in, const int* in_sizes, int n_in,
                              void* d_out, int out_size, void* d_ws,
                              size_t ws_size, hipStream_t stream) {
  const float* queue = (const float*)d_in[0];
  const float* key   = (const float*)d_in[1];
  const float* value = (const float*)d_in[2];
  float* S = (float*)d_out;
  float* T = S + (size_t)BATCH * LQ;

  char* ws = (char*)d_ws;
  const size_t arr = (size_t)BATCH * LP * KD * sizeof(float);  // 117,964,800 B
  float* kn = (float*)(ws);
  float* qn = (float*)(ws + arr);
  size_t off = 2 * arr;
  const size_t nt = (size_t)BATCH * LP * NTILE;  // 331,776 entries
  float* tV1 = (float*)(ws + off); off += nt * 4;
  float* tV2 = (float*)(ws + off); off += nt * 4;
  int* tL1 = (int*)(ws + off); off += nt * 4;
  int* tL2 = (int*)(ws + off); off += nt * 4;
  int* final_l = (int*)(ws + off); off += (size_t)BATCH * LQ * 4;
  int* flag_list = (int*)(ws + off); off += (size_t)BATCH * LQ * 4;
  off = (off + 255) & ~(size_t)255;
  int* flag_cnt = (int*)(ws + off);

  hipMemsetAsync(flag_cnt, 0, sizeof(int), stream);
  prep_np_kernel<<<dim3(LP, BATCH), 256, 0, stream>>>(key, kn, 0);
  prep_np_kernel<<<dim3(LP, BATCH), 256, 0, stream>>>(queue, qn, 1);
  brute_mfma_kernel<<<dim3(LP / 128, LP / 128, BATCH), 256, 0, stream>>>(
      kn, qn, tV1, tL1, tV2, tL2);
  finalize32_kernel<<<dim3((LQ + 255) / 256, 1, BATCH), 256, 0, stream>>>(
      tV1, tL1, tV2, tL2, S, final_l, flag_list, flag_cnt);
  refine_kernel<<<dim3(1024), 256, 0, stream>>>(
      flag_list, flag_cnt, kn, qn, S, final_l);
  gather_kernel<<<dim3((LQ + 255) / 256, 16, BATCH), 256, 0, stream>>>(
      final_l, value, T);
}

// Round 8
// 1728.362 us; speedup vs baseline: 3.9557x; 3.9557x over previous
//
#include <hip/hip_runtime.h>
#include <math.h>

#define BATCH 8
#define CH 64
#define HW 96
#define HQ 47
#define LQ 2209         // 47*47
#define LP 2304         // padded to 18*128
#define KD 1600         // 64*25
#define NC9 576         // 64*9
#define NTILE 18        // LP/128 l-tiles
#define BK 32           // k-tile in brute (one MFMA K-step)
#define MARGIN 1e-4f    // split-bf16 screen near-tie window (det-ish bound ~2e-5)
#define RCH 128         // refine l-chunk

typedef __attribute__((ext_vector_type(8))) short short8;   // 8 bf16 (4 VGPR)
typedef __attribute__((ext_vector_type(4))) float f32x4;    // MFMA C/D frag

// ---------------------------------------------------------------------------
// numpy pairwise sum of squares (blocksize 128, 8 accumulators) — exact
// emulation of numpy's pairwise_sum over a contiguous fp32 axis.
// ---------------------------------------------------------------------------
__device__ float np_pairwise_sq(const float* a, int n) {
#pragma clang fp contract(off)
  if (n <= 128) {
    float r[8];
#pragma unroll
    for (int j = 0; j < 8; ++j) { float x = a[j]; r[j] = x * x; }
    int nm8 = n - (n % 8);
    for (int i = 8; i < nm8; i += 8)
#pragma unroll
      for (int j = 0; j < 8; ++j) { float x = a[i + j]; r[j] = r[j] + x * x; }
    float res = ((r[0] + r[1]) + (r[2] + r[3])) + ((r[4] + r[5]) + (r[6] + r[7]));
    for (int i = nm8; i < n; ++i) { float x = a[i]; res = res + x * x; }
    return res;
  }
  int n2 = n / 2;
  n2 -= n2 % 8;
  float s0 = np_pairwise_sq(a, n2);
  float s1 = np_pairwise_sq(a + n2, n - n2);
  return s0 + s1;
}

// ---------------------------------------------------------------------------
// prep: unfold (k=5,p=1,s=2), L2-normalize with numpy-exact fp32 rounding.
// ---------------------------------------------------------------------------
__global__ __launch_bounds__(256) void prep_np_kernel(
    const float* __restrict__ src, float* __restrict__ out, int mode) {
  __shared__ float sRaw[KD];
  __shared__ float sDen;
  const int pos = blockIdx.x;
  const int b = blockIdx.y;
  const int t = threadIdx.x;
  const size_t obase = ((size_t)b * LP + pos) * KD;

  if (pos >= LQ) {
    for (int k = t; k < KD; k += 256) out[obase + k] = 0.f;
    return;
  }
  const int y0 = (pos / HQ) * 2 - 1, x0 = (pos % HQ) * 2 - 1;
  for (int k = t; k < KD; k += 256) {
    const int c = k / 25, r = k % 25, kh = r / 5, kw = r % 5;
    const int y = y0 + kh, x = x0 + kw;
    float v = 0.f;
    if (y >= 0 && y < HW && x >= 0 && x < HW)
      v = src[(((size_t)b * CH + c) * HW + y) * HW + x];
    sRaw[k] = v;
  }
  __syncthreads();
  if (t == 0) {
    float ss;
    if (mode == 0) {
      ss = np_pairwise_sq(sRaw, KD);
    } else {
#pragma clang fp contract(off)
      float acc = 0.f;
      for (int k2 = 0; k2 < KD; ++k2) {
        float x = sRaw[k2];
        float p = x * x;
        acc = acc + p;
      }
      ss = acc;
    }
    float nrm = (float)sqrt((double)ss);
    sDen = fmaxf(nrm, 1e-12f);
  }
  __syncthreads();
  const float den = sDen;
  for (int k = t; k < KD; k += 256) out[obase + k] = sRaw[k] / den;
}

// ---------------------------------------------------------------------------
// split-bf16 helpers: x = hi + lo with |x - (hi+lo)| <= 2^-18 |x|
// ---------------------------------------------------------------------------
__device__ inline void f2bf_split(float x, unsigned& h, unsigned& s) {
  unsigned u = __float_as_uint(x);
  unsigned hr = (u + 0x7fffu + ((u >> 16) & 1u)) >> 16;   // RNE bf16(x)
  h = hr;
  float hf = __uint_as_float(hr << 16);
  float lf = x - hf;                                       // exact (Sterbenz)
  unsigned v = __float_as_uint(lf);
  s = (v + 0x7fffu + ((v >> 16) & 1u)) >> 16;              // RNE bf16(lo)
}

__device__ inline void stage8(short* dh, short* dl, int soff, const float* src) {
  const float4 f0 = *(const float4*)src;
  const float4 f1 = *(const float4*)(src + 4);
  unsigned h[8], l[8];
  f2bf_split(f0.x, h[0], l[0]); f2bf_split(f0.y, h[1], l[1]);
  f2bf_split(f0.z, h[2], l[2]); f2bf_split(f0.w, h[3], l[3]);
  f2bf_split(f1.x, h[4], l[4]); f2bf_split(f1.y, h[5], l[5]);
  f2bf_split(f1.z, h[6], l[6]); f2bf_split(f1.w, h[7], l[7]);
  int4 Hv, Lv;
  Hv.x = (int)(h[0] | (h[1] << 16)); Hv.y = (int)(h[2] | (h[3] << 16));
  Hv.z = (int)(h[4] | (h[5] << 16)); Hv.w = (int)(h[6] | (h[7] << 16));
  Lv.x = (int)(l[0] | (l[1] << 16)); Lv.y = (int)(l[2] | (l[3] << 16));
  Lv.z = (int)(l[4] | (l[5] << 16)); Lv.w = (int)(l[6] | (l[7] << 16));
  *(int4*)((char*)dh + soff * 2) = Hv;   // soff in shorts
  *(int4*)((char*)dl + soff * 2) = Lv;
}

__device__ inline void top2_merge(float& v1, int& l1, float& v2, int& l2,
                                  float b1, int a1, float b2, int a2) {
  if (b1 > v1 || (b1 == v1 && a1 < l1)) {
    float nv2; int nl2;
    if (v1 > b2 || (v1 == b2 && l1 < a2)) { nv2 = v1; nl2 = l1; }
    else { nv2 = b2; nl2 = a2; }
    v1 = b1; l1 = a1; v2 = nv2; l2 = nl2;
  } else if (b1 > v2 || (b1 == v2 && a1 < l2)) {
    v2 = b1; l2 = a1;
  }
}

// ---------------------------------------------------------------------------
// brute_mfma: split-bf16 MFMA screen. x = hi+lo (2 bf16); dot accumulated
// as hi*hi + hi*lo + lo*hi (3 MFMA) into one fp32 acc -> per-dot error
// ~1e-5 det-ish (dropped lo*lo <= 2^-18, repr <= 2*2^-18, fp32 chain).
// Grid (18,18,8); block 256 = 4 waves 2x2; tile 128l x 128q; per wave 64x64
// via 4x4 MFMA 16x16x32 frags; BK=32 k-tiles. Per-tile top-2 as in R5.
// ---------------------------------------------------------------------------
__global__ __launch_bounds__(256) void brute_mfma_kernel(
    const float* __restrict__ kn, const float* __restrict__ qn,
    float* __restrict__ tV1, int* __restrict__ tL1,
    float* __restrict__ tV2, int* __restrict__ tL2) {
  __shared__ __align__(16) short sKh[128 * BK];
  __shared__ __align__(16) short sKl[128 * BK];
  __shared__ __align__(16) short sQh[128 * BK];
  __shared__ __align__(16) short sQl[128 * BK];
  __shared__ float sWv1[2][128];
  __shared__ float sWv2[2][128];
  __shared__ int sWl1[2][128];
  __shared__ int sWl2[2][128];

  const int t = threadIdx.x;
  const int qt = blockIdx.x, lt = blockIdx.y, b = blockIdx.z;
  const int l0 = lt * 128, q0 = qt * 128;
  const int w = t >> 6, lane = t & 63;
  const int wl = w >> 1, wq = w & 1;
  const int cl = lane & 15, g = lane >> 4;

  f32x4 acc[4][4];
#pragma unroll
  for (int i = 0; i < 4; ++i)
#pragma unroll
    for (int j = 0; j < 4; ++j) {
      f32x4 z = {0.f, 0.f, 0.f, 0.f};
      acc[i][j] = z;
    }

  // staging map: 512 slots (128 rows x 4 slots of 8 elems); thread t does
  // slots t and t+256 for both K and Q.
  const int row0 = t >> 2, slot0 = t & 3;
  const int row1 = row0 + 64, slot1 = slot0;
  const int soff0 = row0 * BK + ((slot0 ^ (row0 & 3)) * 8);  // in shorts
  const int soff1 = row1 * BK + ((slot1 ^ (row1 & 3)) * 8);
  const float* kp0 = kn + ((size_t)(b * LP + l0 + row0)) * KD + slot0 * 8;
  const float* kp1 = kn + ((size_t)(b * LP + l0 + row1)) * KD + slot1 * 8;
  const float* qp0 = qn + ((size_t)(b * LP + q0 + row0)) * KD + slot0 * 8;
  const float* qp1 = qn + ((size_t)(b * LP + q0 + row1)) * KD + slot1 * 8;

  for (int c0 = 0; c0 < KD; c0 += BK) {
    __syncthreads();  // previous iteration's frag reads done
    stage8(sKh, sKl, soff0, kp0); stage8(sKh, sKl, soff1, kp1);
    stage8(sQh, sQl, soff0, qp0); stage8(sQh, sQl, soff1, qp1);
    kp0 += BK; kp1 += BK; qp0 += BK; qp1 += BK;
    __syncthreads();
    short8 Ah[4], Al[4], Bh[4], Bl[4];
#pragma unroll
    for (int i = 0; i < 4; ++i) {
      const int ar = wl * 64 + i * 16 + cl;
      const int sa = ar * BK + ((g ^ (ar & 3)) * 8);
      Ah[i] = *(const short8*)(sKh + sa);
      Al[i] = *(const short8*)(sKl + sa);
      const int br = wq * 64 + i * 16 + cl;
      const int sb = br * BK + ((g ^ (br & 3)) * 8);
      Bh[i] = *(const short8*)(sQh + sb);
      Bl[i] = *(const short8*)(sQl + sb);
    }
#pragma unroll
    for (int i = 0; i < 4; ++i)
#pragma unroll
      for (int j = 0; j < 4; ++j) {
        acc[i][j] = __builtin_amdgcn_mfma_f32_16x16x32_bf16(
            Al[i], Bh[j], acc[i][j], 0, 0, 0);
        acc[i][j] = __builtin_amdgcn_mfma_f32_16x16x32_bf16(
            Ah[i], Bl[j], acc[i][j], 0, 0, 0);
        acc[i][j] = __builtin_amdgcn_mfma_f32_16x16x32_bf16(
            Ah[i], Bh[j], acc[i][j], 0, 0, 0);
      }
  }

  // per-wave top-2 over its 64 l's, per q column
#pragma unroll
  for (int j = 0; j < 4; ++j) {
    float v1 = -1e30f, v2 = -1e30f;
    int l1 = 0x7fffffff, l2 = 0x7fffffff;
#pragma unroll
    for (int i = 0; i < 4; ++i)
#pragma unroll
      for (int r = 0; r < 4; ++r) {
        const int ll = l0 + wl * 64 + i * 16 + g * 4 + r;   // ascending per lane
        const float v = (ll < LQ) ? acc[i][j][r] : -1e30f;
        if (v > v1) { v2 = v1; l2 = l1; v1 = v; l1 = ll; }
        else if (v > v2) { v2 = v; l2 = ll; }
      }
#pragma unroll
    for (int m = 16; m < 64; m <<= 1) {
      const float b1 = __shfl_xor(v1, m, 64);
      const int a1 = __shfl_xor(l1, m, 64);
      const float b2 = __shfl_xor(v2, m, 64);
      const int a2 = __shfl_xor(l2, m, 64);
      top2_merge(v1, l1, v2, l2, b1, a1, b2, a2);
    }
    if (g == 0) {
      const int qq = wq * 64 + j * 16 + cl;
      sWv1[wl][qq] = v1; sWl1[wl][qq] = l1;
      sWv2[wl][qq] = v2; sWl2[wl][qq] = l2;
    }
  }
  __syncthreads();
  if (t < 128) {
    float v1 = sWv1[0][t], v2 = sWv2[0][t];
    int l1 = sWl1[0][t], l2 = sWl2[0][t];
    top2_merge(v1, l1, v2, l2, sWv1[1][t], sWl1[1][t], sWv2[1][t], sWl2[1][t]);
    const int q = q0 + t;
    if (q < LQ) {
      const size_t o = ((size_t)b * LP + q) * NTILE + lt;
      tV1[o] = v1; tL1[o] = l1; tV2[o] = v2; tL2[o] = l2;
    }
  }
}

// ---------------------------------------------------------------------------
// finalize32: merge 18 tiles -> screen top-2. Gap >= MARGIN guarantees the
// screen argmax == the reference fp32-rounded argmax. Otherwise flag.
// ---------------------------------------------------------------------------
__global__ __launch_bounds__(256) void finalize32_kernel(
    const float* __restrict__ tV1, const int* __restrict__ tL1,
    const float* __restrict__ tV2, const int* __restrict__ tL2,
    float* __restrict__ S, int* __restrict__ final_l,
    int* __restrict__ flag_list, int* __restrict__ flag_cnt,
    unsigned long long* __restrict__ refineKey) {
  const int q = blockIdx.x * 256 + threadIdx.x;
  const int b = blockIdx.z;
  if (q >= LQ) return;
  const size_t base = ((size_t)b * LP + q) * NTILE;
  float v1 = -1e30f, v2 = -1e30f;
  int l1 = 0x7fffffff, l2 = 0x7fffffff;
  for (int i = 0; i < NTILE; ++i)
    top2_merge(v1, l1, v2, l2, tV1[base + i], tL1[base + i],
               tV2[base + i], tL2[base + i]);
  S[b * LQ + q] = v1;
  final_l[b * LQ + q] = l1;
  if ((v1 - v2) < MARGIN) {
    const int slot = atomicAdd(flag_cnt, 1);
    if (slot < BATCH * LQ) {           // defensive: cannot overflow, but clamp
      flag_list[slot] = b * LQ + q;
      refineKey[b * LQ + q] = 0ull;
    }
  }
}

// ---------------------------------------------------------------------------
// refine: task = (flagged query x 128-l chunk), CHUNK-MAJOR so concurrent
// blocks stream the same kn chunk (L2 reuse). Exact fp64 dots (4-way split
// accumulators; reorder error ~1e-13 << fp32 ulp), fp32-rounded argmax with
// first-index tie rule encoded into a packed u64 atomicMax.
// key = orderable(f) << 32 | (0x7fffffff - l): max f, then min l.
// ---------------------------------------------------------------------------
__global__ __launch_bounds__(256) void refine_kernel(
    const int* __restrict__ flag_list, const int* __restrict__ flag_cnt,
    const float* __restrict__ kn, const float* __restrict__ qn,
    unsigned long long* __restrict__ refineKey) {
  __shared__ float sQrow[KD];
  __shared__ double sPart[128];
  __shared__ float sF[128];
  __shared__ int sL[128];
  int n = *flag_cnt;
  if (n <= 0) return;                  // defensive: uniform early-out
  if (n > BATCH * LQ) n = BATCH * LQ;  // defensive clamp
  const long total = (long)n * NTILE;
  const int t = threadIdx.x;
  const int half = t >> 7, tr = t & 127;
  for (long tau = blockIdx.x; tau < total; tau += gridDim.x) {
    const int chunk = (int)(tau / n);   // chunk-major
    const int e = (int)(tau % n);
    const int bq = flag_list[e];
    const int b = bq / LQ, q = bq % LQ;
    __syncthreads();  // protect previous iteration's sQrow/sF reads
    for (int k = t; k < KD; k += 256)
      sQrow[k] = qn[((size_t)b * LP + q) * KD + k];
    __syncthreads();
    const int l = chunk * RCH + tr;
    double part = 0.0;
    if (l < LQ) {
      const float* kr = kn + ((size_t)b * LP + l) * KD + half * 800;
      const float* qr = sQrow + half * 800;
      double a0 = 0, a1 = 0, a2 = 0, a3 = 0;
      for (int c = 0; c < 800; c += 4) {
        a0 = fma((double)kr[c], (double)qr[c], a0);
        a1 = fma((double)kr[c + 1], (double)qr[c + 1], a1);
        a2 = fma((double)kr[c + 2], (double)qr[c + 2], a2);
        a3 = fma((double)kr[c + 3], (double)qr[c + 3], a3);
      }
      part = (a0 + a1) + (a2 + a3);
    }
    if (half) sPart[tr] = part;
    __syncthreads();
    if (!half) {
      const double tot = part + sPart[tr];
      sF[tr] = (l < LQ) ? (float)tot : -1e30f;
      sL[tr] = l;
    }
    __syncthreads();
    for (int s = 64; s > 0; s >>= 1) {
      if (t < s) {
        const float of = sF[t + s]; const int ol = sL[t + s];
        if (of > sF[t] || (of == sF[t] && ol < sL[t])) { sF[t] = of; sL[t] = ol; }
      }
      __syncthreads();
    }
    if (t == 0) {
      const float bf = sF[0]; const int bl = sL[0];
      const unsigned u = __float_as_uint(bf);
      const unsigned k32 = (bf >= 0.f) ? (u | 0x80000000u) : ~u;
      const unsigned long long key =
          ((unsigned long long)k32 << 32) | (unsigned)(0x7fffffff - bl);
      atomicMax(refineKey + bq, key);
    }
  }
}

// ---------------------------------------------------------------------------
// apply: decode refined winners into S / final_l.
// ---------------------------------------------------------------------------
__global__ __launch_bounds__(256) void apply_kernel(
    const int* __restrict__ flag_list, const int* __restrict__ flag_cnt,
    const unsigned long long* __restrict__ refineKey,
    float* __restrict__ S, int* __restrict__ final_l) {
  int n = *flag_cnt;
  if (n > BATCH * LQ) n = BATCH * LQ;  // defensive clamp
  for (int i = blockIdx.x * 256 + threadIdx.x; i < n; i += gridDim.x * 256) {
    const int bq = flag_list[i];
    const unsigned long long key = refineKey[bq];
    const unsigned k32 = (unsigned)(key >> 32);
    const unsigned u = (k32 & 0x80000000u) ? (k32 & 0x7fffffffu) : ~k32;
    S[bq] = __uint_as_float(u);
    final_l[bq] = 0x7fffffff - (int)(key & 0xffffffffu);
  }
}

// ---------------------------------------------------------------------------
// gather: value patches (k=3,p=1,s=1) at argmax positions.
// ---------------------------------------------------------------------------
__global__ __launch_bounds__(256) void gather_kernel(
    const int* __restrict__ final_l, const float* __restrict__ value,
    float* __restrict__ T) {
  const int q = blockIdx.x * 256 + threadIdx.x;
  const int g = blockIdx.y;
  const int b = blockIdx.z;
  if (q >= LQ) return;
  const int l = final_l[b * LQ + q];
  const int y0 = l / HW - 1;
  const int x0 = l % HW - 1;
#pragma unroll
  for (int cc = 0; cc < 36; ++cc) {
    const int c9 = g * 36 + cc;
    const int c = c9 / 9, r = c9 % 9;
    const int kh = r / 3, kw = r % 3;
    const int y = y0 + kh, x = x0 + kw;
    float v = 0.f;
    if (y >= 0 && y < HW && x >= 0 && x < HW)
      v = value[(((size_t)b * CH + c) * HW + y) * HW + x];
    T[((size_t)(b * NC9 + c9)) * LQ + q] = v;
  }
}

// ---------------------------------------------------------------------------
extern "C" void kernel_launch(void* const* d_in, const int* in_sizes, int n_in,
                              void* d_out, int out_size, void* d_ws,
                              size_t ws_size, hipStream_t stream) {
  const float* queue = (const float*)d_in[0];
  const float* key   = (const float*)d_in[1];
  const float* value = (const float*)d_in[2];
  float* S = (float*)d_out;
  float* T = S + (size_t)BATCH * LQ;

  char* ws = (char*)d_ws;
  const size_t arr = (size_t)BATCH * LP * KD * sizeof(float);  // 117,964,800 B
  float* kn = (float*)(ws);
  float* qn = (float*)(ws + arr);
  size_t off = 2 * arr;
  const size_t nt = (size_t)BATCH * LP * NTILE;  // 331,776 entries
  float* tV1 = (float*)(ws + off); off += nt * 4;
  float* tV2 = (float*)(ws + off); off += nt * 4;
  int* tL1 = (int*)(ws + off); off += nt * 4;
  int* tL2 = (int*)(ws + off); off += nt * 4;
  int* final_l = (int*)(ws + off); off += (size_t)BATCH * LQ * 4;
  int* flag_list = (int*)(ws + off); off += (size_t)BATCH * LQ * 4;
  unsigned long long* refineKey = (unsigned long long*)(ws + off);
  off += (size_t)BATCH * LQ * 8;
  off = (off + 255) & ~(size_t)255;
  int* flag_cnt = (int*)(ws + off);

  hipMemsetAsync(flag_cnt, 0, sizeof(int), stream);
  prep_np_kernel<<<dim3(LP, BATCH), 256, 0, stream>>>(key, kn, 0);
  prep_np_kernel<<<dim3(LP, BATCH), 256, 0, stream>>>(queue, qn, 1);
  brute_mfma_kernel<<<dim3(LP / 128, LP / 128, BATCH), 256, 0, stream>>>(
      kn, qn, tV1, tL1, tV2, tL2);
  finalize32_kernel<<<dim3((LQ + 255) / 256, 1, BATCH), 256, 0, stream>>>(
      tV1, tL1, tV2, tL2, S, final_l, flag_list, flag_cnt, refineKey);
  refine_kernel<<<dim3(4096), 256, 0, stream>>>(
      flag_list, flag_cnt, kn, qn, refineKey);
  apply_kernel<<<dim3(64), 256, 0, stream>>>(
      flag_list, flag_cnt, refineKey, S, final_l);
  gather_kernel<<<dim3((LQ + 255) / 256, 16, BATCH), 256, 0, stream>>>(
      final_l, value, T);
}

// Round 9
// 1395.944 us; speedup vs baseline: 4.8976x; 1.2381x over previous
//
#include <hip/hip_runtime.h>
#include <math.h>

#define BATCH 8
#define CH 64
#define HW 96
#define HQ 47
#define LQ 2209         // 47*47
#define LP 2304         // padded to 18*128
#define KD 1600         // 64*25
#define NC9 576         // 64*9
#define NTILE 18        // LP/128 l-tiles
#define BK 32           // k-tile in brute (one MFMA K-step)
#define ROWW 40         // LDS row stride in shorts (80B): 8 bank phases, 2-way max
#define MARGIN 1e-4f    // split-bf16 screen near-tie window
#define RG 8            // refine queries per block (kn-traffic / RG)

typedef __attribute__((ext_vector_type(8))) short short8;   // 8 bf16 (4 VGPR)
typedef __attribute__((ext_vector_type(4))) float f32x4;    // MFMA C/D frag

// ---------------------------------------------------------------------------
// numpy pairwise sum of squares (blocksize 128, 8 accumulators) — exact
// emulation of numpy's pairwise_sum over a contiguous fp32 axis.
// ---------------------------------------------------------------------------
__device__ float np_pairwise_sq(const float* a, int n) {
#pragma clang fp contract(off)
  if (n <= 128) {
    float r[8];
#pragma unroll
    for (int j = 0; j < 8; ++j) { float x = a[j]; r[j] = x * x; }
    int nm8 = n - (n % 8);
    for (int i = 8; i < nm8; i += 8)
#pragma unroll
      for (int j = 0; j < 8; ++j) { float x = a[i + j]; r[j] = r[j] + x * x; }
    float res = ((r[0] + r[1]) + (r[2] + r[3])) + ((r[4] + r[5]) + (r[6] + r[7]));
    for (int i = nm8; i < n; ++i) { float x = a[i]; res = res + x * x; }
    return res;
  }
  int n2 = n / 2;
  n2 -= n2 % 8;
  float s0 = np_pairwise_sq(a, n2);
  float s1 = np_pairwise_sq(a + n2, n - n2);
  return s0 + s1;
}

// ---------------------------------------------------------------------------
// prep: unfold (k=5,p=1,s=2), L2-normalize with numpy-exact fp32 rounding.
// ---------------------------------------------------------------------------
__global__ __launch_bounds__(256) void prep_np_kernel(
    const float* __restrict__ src, float* __restrict__ out, int mode) {
  __shared__ float sRaw[KD];
  __shared__ float sDen;
  const int pos = blockIdx.x;
  const int b = blockIdx.y;
  const int t = threadIdx.x;
  const size_t obase = ((size_t)b * LP + pos) * KD;

  if (pos >= LQ) {
    for (int k = t; k < KD; k += 256) out[obase + k] = 0.f;
    return;
  }
  const int y0 = (pos / HQ) * 2 - 1, x0 = (pos % HQ) * 2 - 1;
  for (int k = t; k < KD; k += 256) {
    const int c = k / 25, r = k % 25, kh = r / 5, kw = r % 5;
    const int y = y0 + kh, x = x0 + kw;
    float v = 0.f;
    if (y >= 0 && y < HW && x >= 0 && x < HW)
      v = src[(((size_t)b * CH + c) * HW + y) * HW + x];
    sRaw[k] = v;
  }
  __syncthreads();
  if (t == 0) {
    float ss;
    if (mode == 0) {
      ss = np_pairwise_sq(sRaw, KD);
    } else {
#pragma clang fp contract(off)
      float acc = 0.f;
      for (int k2 = 0; k2 < KD; ++k2) {
        float x = sRaw[k2];
        float p = x * x;
        acc = acc + p;
      }
      ss = acc;
    }
    float nrm = (float)sqrt((double)ss);
    sDen = fmaxf(nrm, 1e-12f);
  }
  __syncthreads();
  const float den = sDen;
  for (int k = t; k < KD; k += 256) out[obase + k] = sRaw[k] / den;
}

// ---------------------------------------------------------------------------
// split staging via v_cvt_pk_bf16_f32 (no builtin on gfx950 -> inline asm):
// hi = cvt_pk(x0,x1); lo_i = x_i - bf2f(hi_i); lo = cvt_pk(lo0,lo1).
// ~3 VALU/elem vs ~10 for manual RNE. Screen needs no specific rounding —
// any deterministic cvt rounding keeps the error budget (<< MARGIN).
// ---------------------------------------------------------------------------
__device__ inline void stage8_pk(short* dh, short* dl, int soff,
                                 const float* __restrict__ src) {
  const float4 f0 = *(const float4*)src;
  const float4 f1 = *(const float4*)(src + 4);
  const float x[8] = {f0.x, f0.y, f0.z, f0.w, f1.x, f1.y, f1.z, f1.w};
  int hp[4], lp[4];
#pragma unroll
  for (int p = 0; p < 4; ++p) {
    int h;
    asm("v_cvt_pk_bf16_f32 %0, %1, %2" : "=v"(h) : "v"(x[2 * p]), "v"(x[2 * p + 1]));
    hp[p] = h;
    const float h0 = __uint_as_float(((unsigned)h) << 16);        // src0 -> low16
    const float h1 = __uint_as_float(((unsigned)h) & 0xFFFF0000u);
    const float l0 = x[2 * p] - h0;
    const float l1 = x[2 * p + 1] - h1;
    int l;
    asm("v_cvt_pk_bf16_f32 %0, %1, %2" : "=v"(l) : "v"(l0), "v"(l1));
    lp[p] = l;
  }
  *(int4*)(dh + soff) = *(int4*)hp;   // soff in shorts, 16B-aligned
  *(int4*)(dl + soff) = *(int4*)lp;
}

__device__ inline void top2_merge(float& v1, int& l1, float& v2, int& l2,
                                  float b1, int a1, float b2, int a2) {
  if (b1 > v1 || (b1 == v1 && a1 < l1)) {
    float nv2; int nl2;
    if (v1 > b2 || (v1 == b2 && l1 < a2)) { nv2 = v1; nl2 = l1; }
    else { nv2 = b2; nl2 = a2; }
    v1 = b1; l1 = a1; v2 = nv2; l2 = nl2;
  } else if (b1 > v2 || (b1 == v2 && a1 < l2)) {
    v2 = b1; l2 = a1;
  }
}

// ---------------------------------------------------------------------------
// brute_mfma: split-bf16 MFMA screen (hi*hi + hi*lo + lo*hi, fp32 acc).
// LDS rows padded to ROWW=40 shorts (80B): row stride 20 words -> 8 bank
// phases -> <=2-way conflicts on both ds_write_b128 and frag ds_read_b128
// (replaces the R8 XOR swizzle that still left 4-way aliasing).
// ---------------------------------------------------------------------------
__global__ __launch_bounds__(256) void brute_mfma_kernel(
    const float* __restrict__ kn, const float* __restrict__ qn,
    float* __restrict__ tV1, int* __restrict__ tL1,
    float* __restrict__ tV2, int* __restrict__ tL2) {
  __shared__ __align__(16) short sKh[128 * ROWW];
  __shared__ __align__(16) short sKl[128 * ROWW];
  __shared__ __align__(16) short sQh[128 * ROWW];
  __shared__ __align__(16) short sQl[128 * ROWW];
  __shared__ float sWv1[2][128];
  __shared__ float sWv2[2][128];
  __shared__ int sWl1[2][128];
  __shared__ int sWl2[2][128];

  const int t = threadIdx.x;
  const int qt = blockIdx.x, lt = blockIdx.y, b = blockIdx.z;
  const int l0 = lt * 128, q0 = qt * 128;
  const int w = t >> 6, lane = t & 63;
  const int wl = w >> 1, wq = w & 1;
  const int cl = lane & 15, g = lane >> 4;

  f32x4 acc[4][4];
#pragma unroll
  for (int i = 0; i < 4; ++i)
#pragma unroll
    for (int j = 0; j < 4; ++j) {
      f32x4 z = {0.f, 0.f, 0.f, 0.f};
      acc[i][j] = z;
    }

  // staging map: 512 slots (128 rows x 4 slots of 8 elems); thread t does
  // slots t and t+256 for both K and Q.
  const int row0 = t >> 2, slot0 = t & 3;
  const int row1 = row0 + 64;
  const int soff0 = row0 * ROWW + slot0 * 8;   // shorts; 16B-aligned
  const int soff1 = row1 * ROWW + slot0 * 8;
  const float* kp0 = kn + ((size_t)(b * LP + l0 + row0)) * KD + slot0 * 8;
  const float* kp1 = kn + ((size_t)(b * LP + l0 + row1)) * KD + slot0 * 8;
  const float* qp0 = qn + ((size_t)(b * LP + q0 + row0)) * KD + slot0 * 8;
  const float* qp1 = qn + ((size_t)(b * LP + q0 + row1)) * KD + slot0 * 8;

  for (int c0 = 0; c0 < KD; c0 += BK) {
    __syncthreads();  // previous iteration's frag reads done
    stage8_pk(sKh, sKl, soff0, kp0); stage8_pk(sKh, sKl, soff1, kp1);
    stage8_pk(sQh, sQl, soff0, qp0); stage8_pk(sQh, sQl, soff1, qp1);
    kp0 += BK; kp1 += BK; qp0 += BK; qp1 += BK;
    __syncthreads();
    short8 Ah[4], Al[4], Bh[4], Bl[4];
#pragma unroll
    for (int i = 0; i < 4; ++i) {
      const int ar = wl * 64 + i * 16 + cl;
      const int sa = ar * ROWW + g * 8;
      Ah[i] = *(const short8*)(sKh + sa);
      Al[i] = *(const short8*)(sKl + sa);
      const int br = wq * 64 + i * 16 + cl;
      const int sb = br * ROWW + g * 8;
      Bh[i] = *(const short8*)(sQh + sb);
      Bl[i] = *(const short8*)(sQl + sb);
    }
#pragma unroll
    for (int i = 0; i < 4; ++i)
#pragma unroll
      for (int j = 0; j < 4; ++j) {
        acc[i][j] = __builtin_amdgcn_mfma_f32_16x16x32_bf16(
            Al[i], Bh[j], acc[i][j], 0, 0, 0);
        acc[i][j] = __builtin_amdgcn_mfma_f32_16x16x32_bf16(
            Ah[i], Bl[j], acc[i][j], 0, 0, 0);
        acc[i][j] = __builtin_amdgcn_mfma_f32_16x16x32_bf16(
            Ah[i], Bh[j], acc[i][j], 0, 0, 0);
      }
  }

  // per-wave top-2 over its 64 l's, per q column
#pragma unroll
  for (int j = 0; j < 4; ++j) {
    float v1 = -1e30f, v2 = -1e30f;
    int l1 = 0x7fffffff, l2 = 0x7fffffff;
#pragma unroll
    for (int i = 0; i < 4; ++i)
#pragma unroll
      for (int r = 0; r < 4; ++r) {
        const int ll = l0 + wl * 64 + i * 16 + g * 4 + r;   // ascending per lane
        const float v = (ll < LQ) ? acc[i][j][r] : -1e30f;
        if (v > v1) { v2 = v1; l2 = l1; v1 = v; l1 = ll; }
        else if (v > v2) { v2 = v; l2 = ll; }
      }
#pragma unroll
    for (int m = 16; m < 64; m <<= 1) {
      const float b1 = __shfl_xor(v1, m, 64);
      const int a1 = __shfl_xor(l1, m, 64);
      const float b2 = __shfl_xor(v2, m, 64);
      const int a2 = __shfl_xor(l2, m, 64);
      top2_merge(v1, l1, v2, l2, b1, a1, b2, a2);
    }
    if (g == 0) {
      const int qq = wq * 64 + j * 16 + cl;
      sWv1[wl][qq] = v1; sWl1[wl][qq] = l1;
      sWv2[wl][qq] = v2; sWl2[wl][qq] = l2;
    }
  }
  __syncthreads();
  if (t < 128) {
    float v1 = sWv1[0][t], v2 = sWv2[0][t];
    int l1 = sWl1[0][t], l2 = sWl2[0][t];
    top2_merge(v1, l1, v2, l2, sWv1[1][t], sWl1[1][t], sWv2[1][t], sWl2[1][t]);
    const int q = q0 + t;
    if (q < LQ) {
      const size_t o = ((size_t)b * LP + q) * NTILE + lt;
      tV1[o] = v1; tL1[o] = l1; tV2[o] = v2; tL2[o] = l2;
    }
  }
}

// ---------------------------------------------------------------------------
// finalize32: merge 18 tiles -> screen top-2; flag near-ties into PER-BATCH
// compacted lists (so refine can group same-batch queries).
// ---------------------------------------------------------------------------
__global__ __launch_bounds__(256) void finalize32_kernel(
    const float* __restrict__ tV1, const int* __restrict__ tL1,
    const float* __restrict__ tV2, const int* __restrict__ tL2,
    float* __restrict__ S, int* __restrict__ final_l,
    int* __restrict__ flag_list, int* __restrict__ flag_cnt,
    unsigned long long* __restrict__ refineKey) {
  const int q = blockIdx.x * 256 + threadIdx.x;
  const int b = blockIdx.z;
  if (q >= LQ) return;
  const size_t base = ((size_t)b * LP + q) * NTILE;
  float v1 = -1e30f, v2 = -1e30f;
  int l1 = 0x7fffffff, l2 = 0x7fffffff;
  for (int i = 0; i < NTILE; ++i)
    top2_merge(v1, l1, v2, l2, tV1[base + i], tL1[base + i],
               tV2[base + i], tL2[base + i]);
  S[b * LQ + q] = v1;
  final_l[b * LQ + q] = l1;
  if ((v1 - v2) < MARGIN) {
    const int slot = atomicAdd(&flag_cnt[b], 1);
    if (slot < LQ) {
      flag_list[b * LQ + slot] = q;
      refineKey[b * LQ + q] = 0ull;
    }
  }
}

// ---------------------------------------------------------------------------
// refine: task = (kn 128-l chunk) x (group of RG flagged queries, same b).
// Block stages RG qn rows in LDS (51.2 KB); each thread owns one l (half the
// c-range) and accumulates RG exact fp64 dots -> kn traffic / RG, and the
// chunk-major order keeps concurrent blocks on the same kn chunk (L2 reuse).
// fp64 per-(half,g) single accumulator, halves summed in fp64, ONE fp32
// round -> exact fp32-rounded dot; argmax first-index rule via packed
// u64 atomicMax key = orderable(f)<<32 | (0x7fffffff - l).
// ---------------------------------------------------------------------------
__global__ __launch_bounds__(256) void refine_kernel(
    const int* __restrict__ flag_list, const int* __restrict__ flag_cnt,
    const float* __restrict__ kn, const float* __restrict__ qn,
    unsigned long long* __restrict__ refineKey) {
  __shared__ float sQ[RG][KD];          // 51.2 KB
  __shared__ double sPartD[128][RG];    // 8 KB
  __shared__ float sAllF[128][RG];      // 4 KB
  __shared__ int sQg[RG];

  const int t = threadIdx.x;
  const int tr = t & 127, half = t >> 7;

  int nb_[BATCH], off_[BATCH + 1];
  off_[0] = 0;
  for (int bb = 0; bb < BATCH; ++bb) {
    int c = flag_cnt[bb];
    if (c < 0) c = 0;
    if (c > LQ) c = LQ;
    nb_[bb] = c;
    off_[bb + 1] = off_[bb] + (c + RG - 1) / RG;
  }
  const int ngtot = off_[BATCH];
  if (ngtot == 0) return;
  const long total = (long)ngtot * NTILE;

  for (long tau = blockIdx.x; tau < total; tau += gridDim.x) {
    const int chunk = (int)(tau / ngtot);          // chunk-major
    const int r = (int)(tau - (long)chunk * ngtot);
    int b = 0;
    while (b + 1 < BATCH && r >= off_[b + 1]) ++b;
    const int grp = r - off_[b];
    const int nb = nb_[b];

    __syncthreads();  // protect previous iteration's sQ/sQg/sAllF reads
    if (t < RG) {
      int j = grp * RG + t;
      if (j >= nb) j = nb - 1;      // pad with duplicate (harmless)
      sQg[t] = flag_list[b * LQ + j];
    }
    __syncthreads();
#pragma unroll
    for (int g2 = 0; g2 < RG; ++g2) {
      const size_t src = ((size_t)b * LP + sQg[g2]) * KD;
      for (int k = t; k < KD; k += 256) sQ[g2][k] = qn[src + k];
    }
    __syncthreads();

    const int l = chunk * 128 + tr;
    double acc[RG];
#pragma unroll
    for (int g2 = 0; g2 < RG; ++g2) acc[g2] = 0.0;
    if (l < LQ) {
      const float* kr = kn + ((size_t)b * LP + l) * KD + half * 800;
      const int cb = half * 800;
      for (int c = 0; c < 800; c += 4) {
        const float4 kv = *(const float4*)(kr + c);
#pragma unroll
        for (int g2 = 0; g2 < RG; ++g2) {
          const float4 qv = *(const float4*)(&sQ[g2][cb + c]);
          acc[g2] = fma((double)kv.x, (double)qv.x, acc[g2]);
          acc[g2] = fma((double)kv.y, (double)qv.y, acc[g2]);
          acc[g2] = fma((double)kv.z, (double)qv.z, acc[g2]);
          acc[g2] = fma((double)kv.w, (double)qv.w, acc[g2]);
        }
      }
    }
    if (half) {
#pragma unroll
      for (int g2 = 0; g2 < RG; ++g2) sPartD[tr][g2] = acc[g2];
    }
    __syncthreads();
    if (!half) {
#pragma unroll
      for (int g2 = 0; g2 < RG; ++g2)
        sAllF[tr][g2] = (l < LQ) ? (float)(acc[g2] + sPartD[tr][g2]) : -1e30f;
    }
    __syncthreads();

    // 32 lanes per g: scan 4 rows each, then shfl-reduce (first-index ties)
    const int g2 = t >> 5, lane5 = t & 31;
    float bf = -1e30f; int bl = 0x7fffffff;
    for (int rr = lane5; rr < 128; rr += 32) {
      const float f = sAllF[rr][g2];
      const int ll = (f > -1e30f) ? (chunk * 128 + rr) : 0x7fffffff;
      if (f > bf || (f == bf && ll < bl)) { bf = f; bl = ll; }
    }
#pragma unroll
    for (int m = 16; m > 0; m >>= 1) {
      const float of = __shfl_xor(bf, m, 32);
      const int ol = __shfl_xor(bl, m, 32);
      if (of > bf || (of == bf && ol < bl)) { bf = of; bl = ol; }
    }
    if (lane5 == 0 && bl != 0x7fffffff) {
      const unsigned u = __float_as_uint(bf);
      const unsigned k32 = (bf >= 0.f) ? (u | 0x80000000u) : ~u;
      const unsigned long long key =
          ((unsigned long long)k32 << 32) | (unsigned)(0x7fffffff - bl);
      atomicMax(refineKey + (size_t)b * LQ + sQg[g2], key);
    }
  }
}

// ---------------------------------------------------------------------------
// apply: decode refined winners into S / final_l (per-batch lists).
// ---------------------------------------------------------------------------
__global__ __launch_bounds__(256) void apply_kernel(
    const int* __restrict__ flag_list, const int* __restrict__ flag_cnt,
    const unsigned long long* __restrict__ refineKey,
    float* __restrict__ S, int* __restrict__ final_l) {
  for (int idx = blockIdx.x * 256 + threadIdx.x; idx < BATCH * LQ;
       idx += gridDim.x * 256) {
    const int b = idx / LQ, j = idx % LQ;
    int n = flag_cnt[b]; if (n > LQ) n = LQ;
    if (j >= n) continue;
    const int q = flag_list[idx];
    const unsigned long long key = refineKey[(size_t)b * LQ + q];
    const unsigned k32 = (unsigned)(key >> 32);
    const unsigned u = (k32 & 0x80000000u) ? (k32 & 0x7fffffffu) : ~k32;
    S[b * LQ + q] = __uint_as_float(u);
    final_l[b * LQ + q] = 0x7fffffff - (int)(key & 0xffffffffu);
  }
}

// ---------------------------------------------------------------------------
// gather: value patches (k=3,p=1,s=1) at argmax positions.
// ---------------------------------------------------------------------------
__global__ __launch_bounds__(256) void gather_kernel(
    const int* __restrict__ final_l, const float* __restrict__ value,
    float* __restrict__ T) {
  const int q = blockIdx.x * 256 + threadIdx.x;
  const int g = blockIdx.y;
  const int b = blockIdx.z;
  if (q >= LQ) return;
  const int l = final_l[b * LQ + q];
  const int y0 = l / HW - 1;
  const int x0 = l % HW - 1;
#pragma unroll
  for (int cc = 0; cc < 36; ++cc) {
    const int c9 = g * 36 + cc;
    const int c = c9 / 9, r = c9 % 9;
    const int kh = r / 3, kw = r % 3;
    const int y = y0 + kh, x = x0 + kw;
    float v = 0.f;
    if (y >= 0 && y < HW && x >= 0 && x < HW)
      v = value[(((size_t)b * CH + c) * HW + y) * HW + x];
    T[((size_t)(b * NC9 + c9)) * LQ + q] = v;
  }
}

// ---------------------------------------------------------------------------
extern "C" void kernel_launch(void* const* d_in, const int* in_sizes, int n_in,
                              void* d_out, int out_size, void* d_ws,
                              size_t ws_size, hipStream_t stream) {
  const float* queue = (const float*)d_in[0];
  const float* key   = (const float*)d_in[1];
  const float* value = (const float*)d_in[2];
  float* S = (float*)d_out;
  float* T = S + (size_t)BATCH * LQ;

  char* ws = (char*)d_ws;
  const size_t arr = (size_t)BATCH * LP * KD * sizeof(float);  // 117,964,800 B
  float* kn = (float*)(ws);
  float* qn = (float*)(ws + arr);
  size_t off = 2 * arr;
  const size_t nt = (size_t)BATCH * LP * NTILE;  // 331,776 entries
  float* tV1 = (float*)(ws + off); off += nt * 4;
  float* tV2 = (float*)(ws + off); off += nt * 4;
  int* tL1 = (int*)(ws + off); off += nt * 4;
  int* tL2 = (int*)(ws + off); off += nt * 4;
  int* final_l = (int*)(ws + off); off += (size_t)BATCH * LQ * 4;
  int* flag_list = (int*)(ws + off); off += (size_t)BATCH * LQ * 4;
  unsigned long long* refineKey = (unsigned long long*)(ws + off);
  off += (size_t)BATCH * LQ * 8;
  off = (off + 255) & ~(size_t)255;
  int* flag_cnt = (int*)(ws + off);   // BATCH ints

  hipMemsetAsync(flag_cnt, 0, BATCH * sizeof(int), stream);
  prep_np_kernel<<<dim3(LP, BATCH), 256, 0, stream>>>(key, kn, 0);
  prep_np_kernel<<<dim3(LP, BATCH), 256, 0, stream>>>(queue, qn, 1);
  brute_mfma_kernel<<<dim3(LP / 128, LP / 128, BATCH), 256, 0, stream>>>(
      kn, qn, tV1, tL1, tV2, tL2);
  finalize32_kernel<<<dim3((LQ + 255) / 256, 1, BATCH), 256, 0, stream>>>(
      tV1, tL1, tV2, tL2, S, final_l, flag_list, flag_cnt, refineKey);
  refine_kernel<<<dim3(4096), 256, 0, stream>>>(
      flag_list, flag_cnt, kn, qn, refineKey);
  apply_kernel<<<dim3(128), 256, 0, stream>>>(
      flag_list, flag_cnt, refineKey, S, final_l);
  gather_kernel<<<dim3((LQ + 255) / 256, 16, BATCH), 256, 0, stream>>>(
      final_l, value, T);
}

// Round 10
// 1268.896 us; speedup vs baseline: 5.3880x; 1.1001x over previous
//
#include <hip/hip_runtime.h>
#include <math.h>

#define BATCH 8
#define CH 64
#define HW 96
#define HQ 47
#define LQ 2209         // 47*47
#define LP 2304         // padded to 18*128
#define KD 1600         // 64*25
#define NC9 576         // 64*9
#define NTILE 18        // LP/128 l-tiles
#define BK 32           // k-tile in brute (one MFMA K-step)
#define MARGIN 5e-5f    // screen near-tie window (worst-case err ~2.1e-5)
#define RG 16           // refine queries per block (kn-traffic / RG)

typedef __attribute__((ext_vector_type(8))) short short8;   // 8 bf16 (4 VGPR)
typedef __attribute__((ext_vector_type(4))) float f32x4;    // MFMA C/D frag

// ---------------------------------------------------------------------------
// numpy pairwise sum of squares (blocksize 128, 8 accumulators) — exact
// emulation of numpy's pairwise_sum over a contiguous fp32 axis.
// ---------------------------------------------------------------------------
__device__ float np_pairwise_sq(const float* a, int n) {
#pragma clang fp contract(off)
  if (n <= 128) {
    float r[8];
#pragma unroll
    for (int j = 0; j < 8; ++j) { float x = a[j]; r[j] = x * x; }
    int nm8 = n - (n % 8);
    for (int i = 8; i < nm8; i += 8)
#pragma unroll
      for (int j = 0; j < 8; ++j) { float x = a[i + j]; r[j] = r[j] + x * x; }
    float res = ((r[0] + r[1]) + (r[2] + r[3])) + ((r[4] + r[5]) + (r[6] + r[7]));
    for (int i = nm8; i < n; ++i) { float x = a[i]; res = res + x * x; }
    return res;
  }
  int n2 = n / 2;
  n2 -= n2 % 8;
  float s0 = np_pairwise_sq(a, n2);
  float s1 = np_pairwise_sq(a + n2, n - n2);
  return s0 + s1;
}

// ---------------------------------------------------------------------------
// prep: unfold (k=5,p=1,s=2), L2-normalize with numpy-exact fp32 rounding.
// ---------------------------------------------------------------------------
__global__ __launch_bounds__(256) void prep_np_kernel(
    const float* __restrict__ src, float* __restrict__ out, int mode) {
  __shared__ float sRaw[KD];
  __shared__ float sDen;
  const int pos = blockIdx.x;
  const int b = blockIdx.y;
  const int t = threadIdx.x;
  const size_t obase = ((size_t)b * LP + pos) * KD;

  if (pos >= LQ) {
    for (int k = t; k < KD; k += 256) out[obase + k] = 0.f;
    return;
  }
  const int y0 = (pos / HQ) * 2 - 1, x0 = (pos % HQ) * 2 - 1;
  for (int k = t; k < KD; k += 256) {
    const int c = k / 25, r = k % 25, kh = r / 5, kw = r % 5;
    const int y = y0 + kh, x = x0 + kw;
    float v = 0.f;
    if (y >= 0 && y < HW && x >= 0 && x < HW)
      v = src[(((size_t)b * CH + c) * HW + y) * HW + x];
    sRaw[k] = v;
  }
  __syncthreads();
  if (t == 0) {
    float ss;
    if (mode == 0) {
      ss = np_pairwise_sq(sRaw, KD);
    } else {
#pragma clang fp contract(off)
      float acc = 0.f;
      for (int k2 = 0; k2 < KD; ++k2) {
        float x = sRaw[k2];
        float p = x * x;
        acc = acc + p;
      }
      ss = acc;
    }
    float nrm = (float)sqrt((double)ss);
    sDen = fmaxf(nrm, 1e-12f);
  }
  __syncthreads();
  const float den = sDen;
  for (int k = t; k < KD; k += 256) out[obase + k] = sRaw[k] / den;
}

// ---------------------------------------------------------------------------
// split staging via v_cvt_pk_bf16_f32: hi = cvt_pk(x0,x1);
// lo_i = x_i - bf2f(hi_i); lo = cvt_pk(lo0,lo1).  ~3 VALU/elem.
// ---------------------------------------------------------------------------
__device__ inline void stage8_pk(short* dh, short* dl, int soff,
                                 const float* __restrict__ src) {
  const float4 f0 = *(const float4*)src;
  const float4 f1 = *(const float4*)(src + 4);
  const float x[8] = {f0.x, f0.y, f0.z, f0.w, f1.x, f1.y, f1.z, f1.w};
  int hp[4], lp[4];
#pragma unroll
  for (int p = 0; p < 4; ++p) {
    int h;
    asm("v_cvt_pk_bf16_f32 %0, %1, %2" : "=v"(h) : "v"(x[2 * p]), "v"(x[2 * p + 1]));
    hp[p] = h;
    const float h0 = __uint_as_float(((unsigned)h) << 16);        // src0 -> low16
    const float h1 = __uint_as_float(((unsigned)h) & 0xFFFF0000u);
    const float l0 = x[2 * p] - h0;
    const float l1 = x[2 * p + 1] - h1;
    int l;
    asm("v_cvt_pk_bf16_f32 %0, %1, %2" : "=v"(l) : "v"(l0), "v"(l1));
    lp[p] = l;
  }
  *(int4*)(dh + soff) = *(int4*)hp;   // soff in shorts, 16B-aligned
  *(int4*)(dl + soff) = *(int4*)lp;
}

__device__ inline void top2_merge(float& v1, int& l1, float& v2, int& l2,
                                  float b1, int a1, float b2, int a2) {
  if (b1 > v1 || (b1 == v1 && a1 < l1)) {
    float nv2; int nl2;
    if (v1 > b2 || (v1 == b2 && l1 < a2)) { nv2 = v1; nl2 = l1; }
    else { nv2 = b2; nl2 = a2; }
    v1 = b1; l1 = a1; v2 = nv2; l2 = nl2;
  } else if (b1 > v2 || (b1 == v2 && a1 < l2)) {
    v2 = b1; l2 = a1;
  }
}

// ---------------------------------------------------------------------------
// brute_mfma: split-bf16 MFMA screen (hi*hi + hi*lo + lo*hi, fp32 acc).
// LDS layout [g][128][8] (g = k-chunk of 8) with row skew (row+2g)&127:
//  - frag read: 16 lanes (one quarter-wave, same g) hit 16 consecutive rows
//    -> 256B contiguous -> conflict-free.
//  - staged write: quarter banks 4*(row+2*slot) mod 32, multiplicity <=2
//    -> free. (R9's ROWW=40 pad was an 8-way READ conflict: 20*row mod 32
//    has period 8 and the g-offsets alias onto the same 8-bank set.)
// ---------------------------------------------------------------------------
__global__ __launch_bounds__(256) void brute_mfma_kernel(
    const float* __restrict__ kn, const float* __restrict__ qn,
    float* __restrict__ tV1, int* __restrict__ tL1,
    float* __restrict__ tV2, int* __restrict__ tL2) {
  __shared__ __align__(16) short sKh[4 * 128 * 8];
  __shared__ __align__(16) short sKl[4 * 128 * 8];
  __shared__ __align__(16) short sQh[4 * 128 * 8];
  __shared__ __align__(16) short sQl[4 * 128 * 8];
  __shared__ float sWv1[2][128];
  __shared__ float sWv2[2][128];
  __shared__ int sWl1[2][128];
  __shared__ int sWl2[2][128];

  const int t = threadIdx.x;
  const int qt = blockIdx.x, lt = blockIdx.y, b = blockIdx.z;
  const int l0 = lt * 128, q0 = qt * 128;
  const int w = t >> 6, lane = t & 63;
  const int wl = w >> 1, wq = w & 1;
  const int cl = lane & 15, g = lane >> 4;

  f32x4 acc[4][4];
#pragma unroll
  for (int i = 0; i < 4; ++i)
#pragma unroll
    for (int j = 0; j < 4; ++j) {
      f32x4 z = {0.f, 0.f, 0.f, 0.f};
      acc[i][j] = z;
    }

  // staging map: thread t stages rows row0=t>>2 and row0+64, k-chunk slot=t&3
  const int row0 = t >> 2, slot0 = t & 3;
  const int row1 = row0 + 64;
  const int soff0 = slot0 * 1024 + (((row0 + 2 * slot0) & 127) * 8); // shorts
  const int soff1 = slot0 * 1024 + (((row1 + 2 * slot0) & 127) * 8);
  const float* kp0 = kn + ((size_t)(b * LP + l0 + row0)) * KD + slot0 * 8;
  const float* kp1 = kn + ((size_t)(b * LP + l0 + row1)) * KD + slot0 * 8;
  const float* qp0 = qn + ((size_t)(b * LP + q0 + row0)) * KD + slot0 * 8;
  const float* qp1 = qn + ((size_t)(b * LP + q0 + row1)) * KD + slot0 * 8;

  for (int c0 = 0; c0 < KD; c0 += BK) {
    __syncthreads();  // previous iteration's frag reads done
    stage8_pk(sKh, sKl, soff0, kp0); stage8_pk(sKh, sKl, soff1, kp1);
    stage8_pk(sQh, sQl, soff0, qp0); stage8_pk(sQh, sQl, soff1, qp1);
    kp0 += BK; kp1 += BK; qp0 += BK; qp1 += BK;
    __syncthreads();
    short8 Ah[4], Al[4], Bh[4], Bl[4];
#pragma unroll
    for (int i = 0; i < 4; ++i) {
      const int ar = wl * 64 + i * 16 + cl;
      const int sa = g * 1024 + (((ar + 2 * g) & 127) * 8);
      Ah[i] = *(const short8*)(sKh + sa);
      Al[i] = *(const short8*)(sKl + sa);
      const int br = wq * 64 + i * 16 + cl;
      const int sb = g * 1024 + (((br + 2 * g) & 127) * 8);
      Bh[i] = *(const short8*)(sQh + sb);
      Bl[i] = *(const short8*)(sQl + sb);
    }
#pragma unroll
    for (int i = 0; i < 4; ++i)
#pragma unroll
      for (int j = 0; j < 4; ++j) {
        acc[i][j] = __builtin_amdgcn_mfma_f32_16x16x32_bf16(
            Al[i], Bh[j], acc[i][j], 0, 0, 0);
        acc[i][j] = __builtin_amdgcn_mfma_f32_16x16x32_bf16(
            Ah[i], Bl[j], acc[i][j], 0, 0, 0);
        acc[i][j] = __builtin_amdgcn_mfma_f32_16x16x32_bf16(
            Ah[i], Bh[j], acc[i][j], 0, 0, 0);
      }
  }

  // per-wave top-2 over its 64 l's, per q column
#pragma unroll
  for (int j = 0; j < 4; ++j) {
    float v1 = -1e30f, v2 = -1e30f;
    int l1 = 0x7fffffff, l2 = 0x7fffffff;
#pragma unroll
    for (int i = 0; i < 4; ++i)
#pragma unroll
      for (int r = 0; r < 4; ++r) {
        const int ll = l0 + wl * 64 + i * 16 + g * 4 + r;   // ascending per lane
        const float v = (ll < LQ) ? acc[i][j][r] : -1e30f;
        if (v > v1) { v2 = v1; l2 = l1; v1 = v; l1 = ll; }
        else if (v > v2) { v2 = v; l2 = ll; }
      }
#pragma unroll
    for (int m = 16; m < 64; m <<= 1) {
      const float b1 = __shfl_xor(v1, m, 64);
      const int a1 = __shfl_xor(l1, m, 64);
      const float b2 = __shfl_xor(v2, m, 64);
      const int a2 = __shfl_xor(l2, m, 64);
      top2_merge(v1, l1, v2, l2, b1, a1, b2, a2);
    }
    if (g == 0) {
      const int qq = wq * 64 + j * 16 + cl;
      sWv1[wl][qq] = v1; sWl1[wl][qq] = l1;
      sWv2[wl][qq] = v2; sWl2[wl][qq] = l2;
    }
  }
  __syncthreads();
  if (t < 128) {
    float v1 = sWv1[0][t], v2 = sWv2[0][t];
    int l1 = sWl1[0][t], l2 = sWl2[0][t];
    top2_merge(v1, l1, v2, l2, sWv1[1][t], sWl1[1][t], sWv2[1][t], sWl2[1][t]);
    const int q = q0 + t;
    if (q < LQ) {
      const size_t o = ((size_t)b * LP + q) * NTILE + lt;
      tV1[o] = v1; tL1[o] = l1; tV2[o] = v2; tL2[o] = l2;
    }
  }
}

// ---------------------------------------------------------------------------
// finalize32: merge 18 tiles -> screen top-2; flag near-ties into PER-BATCH
// compacted lists (so refine can group same-batch queries).
// ---------------------------------------------------------------------------
__global__ __launch_bounds__(256) void finalize32_kernel(
    const float* __restrict__ tV1, const int* __restrict__ tL1,
    const float* __restrict__ tV2, const int* __restrict__ tL2,
    float* __restrict__ S, int* __restrict__ final_l,
    int* __restrict__ flag_list, int* __restrict__ flag_cnt,
    unsigned long long* __restrict__ refineKey) {
  const int q = blockIdx.x * 256 + threadIdx.x;
  const int b = blockIdx.z;
  if (q >= LQ) return;
  const size_t base = ((size_t)b * LP + q) * NTILE;
  float v1 = -1e30f, v2 = -1e30f;
  int l1 = 0x7fffffff, l2 = 0x7fffffff;
  for (int i = 0; i < NTILE; ++i)
    top2_merge(v1, l1, v2, l2, tV1[base + i], tL1[base + i],
               tV2[base + i], tL2[base + i]);
  S[b * LQ + q] = v1;
  final_l[b * LQ + q] = l1;
  if ((v1 - v2) < MARGIN) {
    const int slot = atomicAdd(&flag_cnt[b], 1);
    if (slot < LQ) {
      flag_list[b * LQ + slot] = q;
      refineKey[b * LQ + q] = 0ull;
    }
  }
}

// ---------------------------------------------------------------------------
// refine: task = (kn 128-l chunk) x (group of RG=16 flagged queries, same b).
// Block stages RG qn rows in LDS (102.4 KB; gfx950 static LDS budget 160KB);
// each thread owns one l (half the c-range), accumulates RG exact fp64 dots
// (qn reads are wave-uniform -> LDS broadcast, free). kn traffic / RG;
// chunk-major order keeps concurrent blocks on the same kn chunks (L2/L3).
// Exact fp32-rounded argmax, first-index ties, via packed u64 atomicMax.
// ---------------------------------------------------------------------------
__global__ __launch_bounds__(256) void refine_kernel(
    const int* __restrict__ flag_list, const int* __restrict__ flag_cnt,
    const float* __restrict__ kn, const float* __restrict__ qn,
    unsigned long long* __restrict__ refineKey) {
  __shared__ float sQ[RG][KD];          // 102.4 KB
  __shared__ double sPartD[128][RG];    // 16 KB
  __shared__ float sAllF[128][RG];      // 8 KB
  __shared__ int sQg[RG];

  const int t = threadIdx.x;
  const int tr = t & 127, half = t >> 7;

  int nb_[BATCH], off_[BATCH + 1];
  off_[0] = 0;
  for (int bb = 0; bb < BATCH; ++bb) {
    int c = flag_cnt[bb];
    if (c < 0) c = 0;
    if (c > LQ) c = LQ;
    nb_[bb] = c;
    off_[bb + 1] = off_[bb] + (c + RG - 1) / RG;
  }
  const int ngtot = off_[BATCH];
  if (ngtot == 0) return;
  const long total = (long)ngtot * NTILE;

  for (long tau = blockIdx.x; tau < total; tau += gridDim.x) {
    const int chunk = (int)(tau / ngtot);          // chunk-major
    const int r = (int)(tau - (long)chunk * ngtot);
    int b = 0;
    while (b + 1 < BATCH && r >= off_[b + 1]) ++b;
    const int grp = r - off_[b];
    const int nb = nb_[b];

    __syncthreads();  // protect previous iteration's sQ/sQg/sAllF reads
    if (t < RG) {
      int j = grp * RG + t;
      if (j >= nb) j = nb - 1;      // pad with duplicate (harmless)
      sQg[t] = flag_list[b * LQ + j];
    }
    __syncthreads();
#pragma unroll
    for (int g2 = 0; g2 < RG; ++g2) {
      const size_t src = ((size_t)b * LP + sQg[g2]) * KD;
      for (int k = t; k < KD; k += 256) sQ[g2][k] = qn[src + k];
    }
    __syncthreads();

    const int l = chunk * 128 + tr;
    double acc[RG];
#pragma unroll
    for (int g2 = 0; g2 < RG; ++g2) acc[g2] = 0.0;
    if (l < LQ) {
      const float* kr = kn + ((size_t)b * LP + l) * KD + half * 800;
      const int cb = half * 800;
      for (int c = 0; c < 800; c += 4) {
        const float4 kv = *(const float4*)(kr + c);
#pragma unroll
        for (int g2 = 0; g2 < RG; ++g2) {
          const float4 qv = *(const float4*)(&sQ[g2][cb + c]);
          acc[g2] = fma((double)kv.x, (double)qv.x, acc[g2]);
          acc[g2] = fma((double)kv.y, (double)qv.y, acc[g2]);
          acc[g2] = fma((double)kv.z, (double)qv.z, acc[g2]);
          acc[g2] = fma((double)kv.w, (double)qv.w, acc[g2]);
        }
      }
    }
    if (half) {
#pragma unroll
      for (int g2 = 0; g2 < RG; ++g2) sPartD[tr][g2] = acc[g2];
    }
    __syncthreads();
    if (!half) {
#pragma unroll
      for (int g2 = 0; g2 < RG; ++g2)
        sAllF[tr][g2] = (l < LQ) ? (float)(acc[g2] + sPartD[tr][g2]) : -1e30f;
    }
    __syncthreads();

    // 16 lanes per g2: scan 8 rows each, then shfl-reduce (first-index ties)
    const int g2 = t >> 4, lane4 = t & 15;
    float bf = -1e30f; int bl = 0x7fffffff;
    for (int rr = lane4; rr < 128; rr += 16) {
      const float f = sAllF[rr][g2];
      const int ll = (f > -1e30f) ? (chunk * 128 + rr) : 0x7fffffff;
      if (f > bf || (f == bf && ll < bl)) { bf = f; bl = ll; }
    }
#pragma unroll
    for (int m = 8; m > 0; m >>= 1) {
      const float of = __shfl_xor(bf, m, 16);
      const int ol = __shfl_xor(bl, m, 16);
      if (of > bf || (of == bf && ol < bl)) { bf = of; bl = ol; }
    }
    if (lane4 == 0 && bl != 0x7fffffff) {
      const unsigned u = __float_as_uint(bf);
      const unsigned k32 = (bf >= 0.f) ? (u | 0x80000000u) : ~u;
      const unsigned long long key =
          ((unsigned long long)k32 << 32) | (unsigned)(0x7fffffff - bl);
      atomicMax(refineKey + (size_t)b * LQ + sQg[g2], key);
    }
  }
}

// ---------------------------------------------------------------------------
// apply: decode refined winners into S / final_l (per-batch lists).
// ---------------------------------------------------------------------------
__global__ __launch_bounds__(256) void apply_kernel(
    const int* __restrict__ flag_list, const int* __restrict__ flag_cnt,
    const unsigned long long* __restrict__ refineKey,
    float* __restrict__ S, int* __restrict__ final_l) {
  for (int idx = blockIdx.x * 256 + threadIdx.x; idx < BATCH * LQ;
       idx += gridDim.x * 256) {
    const int b = idx / LQ, j = idx % LQ;
    int n = flag_cnt[b]; if (n > LQ) n = LQ;
    if (j >= n) continue;
    const int q = flag_list[idx];
    const unsigned long long key = refineKey[(size_t)b * LQ + q];
    const unsigned k32 = (unsigned)(key >> 32);
    const unsigned u = (k32 & 0x80000000u) ? (k32 & 0x7fffffffu) : ~k32;
    S[b * LQ + q] = __uint_as_float(u);
    final_l[b * LQ + q] = 0x7fffffff - (int)(key & 0xffffffffu);
  }
}

// ---------------------------------------------------------------------------
// gather: value patches (k=3,p=1,s=1) at argmax positions.
// ---------------------------------------------------------------------------
__global__ __launch_bounds__(256) void gather_kernel(
    const int* __restrict__ final_l, const float* __restrict__ value,
    float* __restrict__ T) {
  const int q = blockIdx.x * 256 + threadIdx.x;
  const int g = blockIdx.y;
  const int b = blockIdx.z;
  if (q >= LQ) return;
  const int l = final_l[b * LQ + q];
  const int y0 = l / HW - 1;
  const int x0 = l % HW - 1;
#pragma unroll
  for (int cc = 0; cc < 36; ++cc) {
    const int c9 = g * 36 + cc;
    const int c = c9 / 9, r = c9 % 9;
    const int kh = r / 3, kw = r % 3;
    const int y = y0 + kh, x = x0 + kw;
    float v = 0.f;
    if (y >= 0 && y < HW && x >= 0 && x < HW)
      v = value[(((size_t)b * CH + c) * HW + y) * HW + x];
    T[((size_t)(b * NC9 + c9)) * LQ + q] = v;
  }
}

// ---------------------------------------------------------------------------
extern "C" void kernel_launch(void* const* d_in, const int* in_sizes, int n_in,
                              void* d_out, int out_size, void* d_ws,
                              size_t ws_size, hipStream_t stream) {
  const float* queue = (const float*)d_in[0];
  const float* key   = (const float*)d_in[1];
  const float* value = (const float*)d_in[2];
  float* S = (float*)d_out;
  float* T = S + (size_t)BATCH * LQ;

  char* ws = (char*)d_ws;
  const size_t arr = (size_t)BATCH * LP * KD * sizeof(float);  // 117,964,800 B
  float* kn = (float*)(ws);
  float* qn = (float*)(ws + arr);
  size_t off = 2 * arr;
  const size_t nt = (size_t)BATCH * LP * NTILE;  // 331,776 entries
  float* tV1 = (float*)(ws + off); off += nt * 4;
  float* tV2 = (float*)(ws + off); off += nt * 4;
  int* tL1 = (int*)(ws + off); off += nt * 4;
  int* tL2 = (int*)(ws + off); off += nt * 4;
  int* final_l = (int*)(ws + off); off += (size_t)BATCH * LQ * 4;
  int* flag_list = (int*)(ws + off); off += (size_t)BATCH * LQ * 4;
  unsigned long long* refineKey = (unsigned long long*)(ws + off);
  off += (size_t)BATCH * LQ * 8;
  off = (off + 255) & ~(size_t)255;
  int* flag_cnt = (int*)(ws + off);   // BATCH ints

  hipMemsetAsync(flag_cnt, 0, BATCH * sizeof(int), stream);
  prep_np_kernel<<<dim3(LP, BATCH), 256, 0, stream>>>(key, kn, 0);
  prep_np_kernel<<<dim3(LP, BATCH), 256, 0, stream>>>(queue, qn, 1);
  brute_mfma_kernel<<<dim3(LP / 128, LP / 128, BATCH), 256, 0, stream>>>(
      kn, qn, tV1, tL1, tV2, tL2);
  finalize32_kernel<<<dim3((LQ + 255) / 256, 1, BATCH), 256, 0, stream>>>(
      tV1, tL1, tV2, tL2, S, final_l, flag_list, flag_cnt, refineKey);
  refine_kernel<<<dim3(4096), 256, 0, stream>>>(
      flag_list, flag_cnt, kn, qn, refineKey);
  apply_kernel<<<dim3(128), 256, 0, stream>>>(
      flag_list, flag_cnt, refineKey, S, final_l);
  gather_kernel<<<dim3((LQ + 255) / 256, 16, BATCH), 256, 0, stream>>>(
      final_l, value, T);
}